// Round 10
// baseline (403.873 us; speedup 1.0000x reference)
//
#include <hip/hip_runtime.h>
#include <math.h>

#define N_WORD 50000
#define N_DOC  10000
#define E_WW   800000
#define E_WD   320000
#define D_IN   256
#define D_H    128

#define NPB    256            // nodes per bucket
#define NBK_W  196            // ceil(50000/256)
#define NBK_D  40             // ceil(10000/256)
#define BKT    (3 * NBK_W + NBK_D)   // 628 buckets total
#define EPB    8192           // edges per bin block (LDS-sorted)
#define NBLK_WW 98            // ceil(800000/8192)
#define NBLK_WD 40            // ceil(320000/8192)
#define NBLK_TOT (2 * NBLK_WW + 2 * NBLK_WD)   // 276
#define PACK_BLKS 145

// per-bucket staging caps (binomial mean + >10 sigma; graph fixed by seed)
#define CAP_WW  4736          // mean 4082, sigma ~64
#define CAP_WDR 2176          // mean 1633, sigma ~40
#define CAP_WD  8960          // mean 8000, sigma ~89

#define WSTRIP ((N_WORD + 63) / 64)  // 782
#define DSTRIP ((N_DOC + 63) / 64)   // 157
#define NSTRIP (WSTRIP + DSTRIP)     // 939

#define GMB    ((N_WORD + N_DOC + 3) / 4)   // 15000 blocks per gather pass

typedef __attribute__((ext_vector_type(8))) short short8;
typedef __attribute__((ext_vector_type(4))) float f32x4;
typedef __attribute__((ext_vector_type(2))) float f32x2;

__device__ inline unsigned short f2bf(float f) {  // fp32 -> bf16 bits, RNE
  unsigned u = __float_as_uint(f);
  u = (u + 0x7fffu + ((u >> 16) & 1u)) >> 16;
  return (unsigned short)u;
}

__device__ inline float bflo(unsigned u) { return __uint_as_float(u << 16); }
__device__ inline float bfhi(unsigned u) { return __uint_as_float(u & 0xffff0000u); }

// ---------------- GEMM body (layer 1): LDS-staged B shared across 4 waves ----
struct G6 { const short* B[6]; unsigned short* C[6]; };

#define BCH 16384   // shorts per staged chunk (32 KB)
#define W2SZ 16384  // shorts per layer-2 matrix (128x128)

template <int ABF, int K>
__device__ void gemm_body(const void* __restrict__ Aw, const void* __restrict__ Ad,
                          const G6& g, int blk, short* __restrict__ Bs) {
  constexpr int KT = K >> 5;          // 8 (K=256)
  constexpr int NCH = KT / 4;         // 32KB chunks per B matrix
  int tid = threadIdx.x;
  int wid = tid >> 6, lane = tid & 63;
  const void* A; int M, row0, h0, h1;
  if (blk < WSTRIP) { A = Aw; M = N_WORD; row0 = blk << 6; h0 = 0; h1 = 4; }
  else { A = Ad; M = N_DOC; row0 = (blk - WSTRIP) << 6; h0 = 4; h1 = 6; }
  int r = lane & 15, quad = lane >> 4;
  int m0 = row0 + wid * 16;
  int mA = m0 + r; if (mA >= M) mA = M - 1;   // clamp: garbage rows never stored
  short8 afr[KT];
  if (ABF) {
    const short* ap = (const short*)A + (size_t)mA * K + quad * 8;
#pragma unroll
    for (int kt = 0; kt < KT; ++kt) afr[kt] = *(const short8*)(ap + kt * 32);
  } else {
    const float* ap = (const float*)A + (size_t)mA * K + quad * 8;
#pragma unroll
    for (int kt = 0; kt < KT; ++kt) {
      float4 a0 = *(const float4*)(ap + kt * 32);
      float4 a1 = *(const float4*)(ap + kt * 32 + 4);
      short8 v;
      v[0] = (short)f2bf(a0.x); v[1] = (short)f2bf(a0.y);
      v[2] = (short)f2bf(a0.z); v[3] = (short)f2bf(a0.w);
      v[4] = (short)f2bf(a1.x); v[5] = (short)f2bf(a1.y);
      v[6] = (short)f2bf(a1.z); v[7] = (short)f2bf(a1.w);
      afr[kt] = v;
    }
  }
  for (int h = h0; h < h1; ++h) {
    const short* Bp = g.B[h];
    f32x4 acc[8];
#pragma unroll
    for (int nt = 0; nt < 8; ++nt) acc[nt] = (f32x4){0.f, 0.f, 0.f, 0.f};
    for (int c = 0; c < NCH; ++c) {
      const short* src = Bp + (size_t)c * BCH;
#pragma unroll
      for (int i = 0; i < 8; ++i) {
        int o = (i * 256 + tid) * 8;
        *(short8*)(Bs + o) = *(const short8*)(src + o);
      }
      __syncthreads();
#pragma unroll
      for (int ktl = 0; ktl < 4; ++ktl) {
        const short* bbase = Bs + ktl * 4096 + lane * 8;
#pragma unroll
        for (int nt = 0; nt < 8; ++nt) {
          short8 bf = *(const short8*)(bbase + nt * 512);
          acc[nt] = __builtin_amdgcn_mfma_f32_16x16x32_bf16(afr[c * 4 + ktl], bf, acc[nt], 0, 0, 0);
        }
      }
      __syncthreads();   // before next chunk/h overwrites Bs
    }
    // C/D: col = lane&15, row = quad*4 + rr  [m89-verified]
    unsigned short* C = g.C[h];
#pragma unroll
    for (int nt = 0; nt < 8; ++nt)
#pragma unroll
      for (int rr = 0; rr < 4; ++rr) {
        int row = m0 + quad * 4 + rr;
        if (row < M) C[(size_t)row * 128 + nt * 16 + r] = f2bf(acc[nt][rr]);
      }
  }
}

// ---------------- layer-2 fused GEMM: h2 = sum_s B_s * A_s; readout ----------
// A-sources live in FEATURE-SPLIT tables (Lo = dims 0-63, Hi = 64-127).
struct A2 { const unsigned *L[4], *H[4]; };

template <int NS>
__device__ void gemm2_fused(const A2& a,
                            const short* B0, const short* B1,
                            const short* B2, const short* B3,
                            int M, int row0, const float* __restrict__ bias, int ob,
                            const float* __restrict__ lw, const float* __restrict__ lb,
                            float* __restrict__ out, short* __restrict__ Bs) {
  const short* Bm[4] = {B0, B1, B2, B3};
  int tid = threadIdx.x;
  int wid = tid >> 6, lane = tid & 63;
  int r = lane & 15, quad = lane >> 4;
  int m0 = row0 + wid * 16;
  int mA = m0 + r; if (mA >= M) mA = M - 1;
  short8 afr[NS][4];
#pragma unroll
  for (int s = 0; s < NS; ++s) {
    const short* apL = (const short*)a.L[s] + (size_t)mA * 64 + quad * 8;
    const short* apH = (const short*)a.H[s] + (size_t)mA * 64 + quad * 8;
    afr[s][0] = *(const short8*)apL;
    afr[s][1] = *(const short8*)(apL + 32);
    afr[s][2] = *(const short8*)apH;
    afr[s][3] = *(const short8*)(apH + 32);
  }
  f32x4 acc[8];
#pragma unroll
  for (int nt = 0; nt < 8; ++nt) acc[nt] = (f32x4){0.f, 0.f, 0.f, 0.f};
#pragma unroll
  for (int s = 0; s < NS; ++s) {
    const short* src = Bm[s];
#pragma unroll
    for (int i = 0; i < 8; ++i) {
      int o = (i * 256 + tid) * 8;
      *(short8*)(Bs + o) = *(const short8*)(src + o);
    }
    __syncthreads();
#pragma unroll
    for (int ktl = 0; ktl < 4; ++ktl) {
      const short* bbase = Bs + ktl * 4096 + lane * 8;
#pragma unroll
      for (int nt = 0; nt < 8; ++nt) {
        short8 bf = *(const short8*)(bbase + nt * 512);
        acc[nt] = __builtin_amdgcn_mfma_f32_16x16x32_bf16(afr[s][ktl], bf, acc[nt], 0, 0, 0);
      }
    }
    __syncthreads();
  }
  // epilogue: per row, p = sum_col relu(acc+bias)*lw; reduce over 16 col-lanes
  float bsv[8], lwv[8];
#pragma unroll
  for (int nt = 0; nt < 8; ++nt) { bsv[nt] = bias[nt * 16 + r]; lwv[nt] = lw[nt * 16 + r]; }
  float lbv = lb[0];
#pragma unroll
  for (int rr = 0; rr < 4; ++rr) {
    float p = 0.f;
#pragma unroll
    for (int nt = 0; nt < 8; ++nt) {
      float v = acc[nt][rr] + bsv[nt];
      v = fmaxf(v, 0.f);
      p += v * lwv[nt];
    }
    p += __shfl_xor(p, 1, 64);
    p += __shfl_xor(p, 2, 64);
    p += __shfl_xor(p, 4, 64);
    p += __shfl_xor(p, 8, 64);
    int row = m0 + quad * 4 + rr;
    if (r == 0 && row < M) out[ob + row] = 1.0f / (1.0f + expf(-(p + lbv)));
  }
}

__global__ __launch_bounds__(256, 2) void gemm2f_kernel(
    A2 aw, A2 ad, const short* __restrict__ Bp2, const float* __restrict__ bsW,
    const float* __restrict__ bsD, const float* __restrict__ lw,
    const float* __restrict__ lb, float* __restrict__ out) {
  __shared__ short Bs[W2SZ];          // 32 KB
  int blk = blockIdx.x;
  if (blk < WSTRIP)
    gemm2_fused<4>(aw, Bp2, Bp2 + W2SZ, Bp2 + 2 * W2SZ, Bp2 + 4 * W2SZ,
                   N_WORD, blk << 6, bsW, 0, lw, lb, out, Bs);
  else
    gemm2_fused<2>(ad, Bp2 + 5 * W2SZ, Bp2 + 3 * W2SZ, nullptr, nullptr,
                   N_DOC, (blk - WSTRIP) << 6, bsD, N_WORD, lw, lb, out, Bs);
}

// ---------------- prep: weight pack + bias combine + bcnt zero ---------------
// Zeroes sentinel rows: full tables (layer-1 gather) + split halves (layer-2).
__global__ __launch_bounds__(256) void prep_kernel(
    const float* __restrict__ Ws1, const float* __restrict__ Wn1,
    const float* __restrict__ Ws2, const float* __restrict__ Wn2,
    short* __restrict__ Bp1, short* __restrict__ Bp2,
    const float* __restrict__ b1, const float* __restrict__ b2,
    float* __restrict__ bs1, float* __restrict__ bs2, int* __restrict__ bcnt,
    unsigned* __restrict__ zA, unsigned* __restrict__ zB,
    unsigned* __restrict__ zC, unsigned* __restrict__ zD,
    unsigned* __restrict__ hA, unsigned* __restrict__ hB,
    unsigned* __restrict__ hC, unsigned* __restrict__ hD) {
  int b = blockIdx.x;
  if (b == PACK_BLKS) {               // zero block
    for (int i = threadIdx.x; i < BKT; i += 256) bcnt[i] = 0;
    if (threadIdx.x < 64) {           // full-table sentinel rows (256 B)
      zA[(size_t)N_WORD * 64 + threadIdx.x] = 0;
      zB[(size_t)N_WORD * 64 + threadIdx.x] = 0;
      zC[(size_t)N_WORD * 64 + threadIdx.x] = 0;
      zD[(size_t)N_DOC * 64 + threadIdx.x] = 0;
    }
    if (threadIdx.x < 32) {           // half-table sentinel rows (128 B)
      hA[(size_t)N_WORD * 32 + threadIdx.x] = 0;
      hB[(size_t)N_WORD * 32 + threadIdx.x] = 0;
      hC[(size_t)N_DOC * 32 + threadIdx.x] = 0;
      hD[(size_t)N_DOC * 32 + threadIdx.x] = 0;
    }
    return;
  }
  int tid = b * 256 + threadIdx.x;
  const int L1T = 6 * 4096;
  const int L2T = 6 * 2048;
  if (tid >= L1T + L2T) {             // bias combine tail
    int t = tid - (L1T + L2T);
    if (t < 128) bs1[t] = b1[t] + b1[128 + t] + b1[384 + t];
    else if (t < 256) { int u = t - 128; bs2[u] = b2[u] + b2[128 + u] + b2[384 + u]; }
    return;
  }
  const float *src0, *src1 = nullptr, *src2 = nullptr;
  short* dstp;
  int kt, nt, lane;
  if (tid < L1T) {
    int mat = tid / 4096, rem = tid % 4096;
    kt = rem / 512; nt = (rem / 64) % 8; lane = rem % 64;
    const int W1 = 256 * 128;
    if (mat == 0) { src0 = Ws1; src1 = Ws1 + W1; src2 = Ws1 + 3 * W1; }
    else if (mat <= 4) src0 = Wn1 + (size_t)(mat - 1) * W1;
    else src0 = Ws1 + 2 * W1;
    dstp = Bp1 + (size_t)mat * W1 + ((size_t)(kt * 8 + nt) * 64 + lane) * 8;
  } else {
    int t2 = tid - L1T;
    int mat = t2 / 2048, rem = t2 % 2048;
    kt = rem / 512; nt = (rem / 64) % 8; lane = rem % 64;
    if (mat == 0) { src0 = Ws2; src1 = Ws2 + W2SZ; src2 = Ws2 + 3 * W2SZ; }
    else if (mat <= 4) src0 = Wn2 + (size_t)(mat - 1) * W2SZ;
    else src0 = Ws2 + 2 * W2SZ;
    dstp = Bp2 + (size_t)mat * W2SZ + ((size_t)(kt * 8 + nt) * 64 + lane) * 8;
  }
  int n = nt * 16 + (lane & 15);
  int kb = kt * 32 + (lane >> 4) * 8;
  short8 v;
#pragma unroll
  for (int j = 0; j < 8; ++j) {
    float f = src0[(size_t)(kb + j) * 128 + n];
    if (src1) f += src1[(size_t)(kb + j) * 128 + n] + src2[(size_t)(kb + j) * 128 + n];
    v[j] = (short)f2bf(f);
  }
  *(short8*)dstp = v;
}

// ---------------- fused [LDS-sorted bin] || layer-1 GEMM ---------------------
__device__ inline void rel_map(int b, const int* wwd, const int* wwrd, const int* wdrd,
                               const int* wdd, const int*& dst, int& E, int& gbase, int& lb) {
  if (b < NBLK_WW) { dst = wwd; E = E_WW; gbase = 0; lb = b; }
  else if (b < 2 * NBLK_WW) { dst = wwrd; E = E_WW; gbase = NBK_W; lb = b - NBLK_WW; }
  else if (b < 2 * NBLK_WW + NBLK_WD) { dst = wdrd; E = E_WD; gbase = 2 * NBK_W; lb = b - 2 * NBLK_WW; }
  else { dst = wdd; E = E_WD; gbase = 3 * NBK_W; lb = b - 2 * NBLK_WW - NBLK_WD; }
}

struct BinLDS {
  unsigned buf[EPB];          // 32 KB sorted edge buffer
  int hist[NBK_W];
  int lofs[NBK_W];
  int gofs[NBK_W];            // global run base - local offset
  int lcur[NBK_W];
  int sm[256];
};

union FusedLDS {
  BinLDS bin;                 // ~36.8 KB (bin blocks)
  short bs[BCH];              // 32 KB B-stage (gemm blocks)
};

__global__ __launch_bounds__(256, 4) void bin_gemm1(
    const int* wws, const int* wwd, const int* wwrs, const int* wwrd,
    const int* wdrs, const int* wdrd, const int* wds, const int* wdd,
    int* bcnt, unsigned* st_ww, unsigned* st_wwr, unsigned* st_wdr, unsigned* st_wd,
    const float* __restrict__ Aw, const float* __restrict__ Ad, G6 g) {
  __shared__ FusedLDS U;
  int b = blockIdx.x;
  if (b >= NBLK_TOT) {
    gemm_body<0, 256>(Aw, Ad, g, b - NBLK_TOT, U.bs);
    return;
  }
  BinLDS& L = U.bin;
  const int* dst; int E, gbase, lb;
  rel_map(b, wwd, wwrd, wdrd, wdd, dst, E, gbase, lb);
  const int* src; unsigned* st; int cap;
  if (b < NBLK_WW) { src = wws; st = st_ww; cap = CAP_WW; }
  else if (b < 2 * NBLK_WW) { src = wwrs; st = st_wwr; cap = CAP_WW; }
  else if (b < 2 * NBLK_WW + NBLK_WD) { src = wdrs; st = st_wdr; cap = CAP_WDR; }
  else { src = wds; st = st_wd; cap = CAP_WD; }
  int tid = threadIdx.x;
  int e0 = lb * EPB;
  int ecnt = E - e0; if (ecnt > EPB) ecnt = EPB;
  if (tid < NBK_W) L.hist[tid] = 0;
  __syncthreads();
  // pass 1: histogram (dst cached in VGPRs for pass 2)
  int dcache[EPB / 256];
#pragma unroll
  for (int k = 0; k < EPB / 256; ++k) {
    int i = e0 + k * 256 + tid;
    int d = (i < E) ? dst[i] : -1;
    dcache[k] = d;
    if (d >= 0) atomicAdd(&L.hist[d >> 8], 1);
  }
  __syncthreads();
  // scan hist -> exclusive local offsets; reserve global runs
  {
    int v = (tid < NBK_W) ? L.hist[tid] : 0;
    L.sm[tid] = v;
    __syncthreads();
    for (int o = 1; o < 256; o <<= 1) {
      int add = (tid >= o) ? L.sm[tid - o] : 0;
      __syncthreads();
      L.sm[tid] += add;
      __syncthreads();
    }
    if (tid < NBK_W) {
      int ex = L.sm[tid] - v;
      L.lofs[tid] = ex;
      L.lcur[tid] = ex;
      int base = v ? atomicAdd(&bcnt[gbase + tid], v) : 0;
      L.gofs[tid] = (int)((size_t)tid * cap) + base - ex;
    }
  }
  __syncthreads();
  // pass 2: counting-sort scatter into LDS
#pragma unroll
  for (int k = 0; k < EPB / 256; ++k) {
    int d = dcache[k];
    if (d >= 0) {
      int i = e0 + k * 256 + tid;
      int bk = d >> 8;
      int p = atomicAdd(&L.lcur[bk], 1);
      L.buf[p] = ((unsigned)bk << 24) | ((unsigned)(d & 255) << 16) |
                 (unsigned)(src[i] & 0xFFFF);
    }
  }
  __syncthreads();
  // coalesced writeout: consecutive LDS entries -> consecutive staging addrs
#pragma unroll
  for (int k = 0; k < EPB / 256; ++k) {
    int p = k * 256 + tid;
    if (p < ecnt) {
      unsigned e = L.buf[p];
      st[L.gofs[e >> 24] + p] = e & 0x00FFFFFFu;
    }
  }
}

// ---------------- place: one block per 256-node bucket -----------------------
struct CSRB {
  const unsigned *st_ww, *st_wwr, *st_wdr, *st_wd;
  unsigned short *c_ww, *c_wwr, *c_wdr, *c_wd;
  int *rp_ww, *rp_wwr, *rp_wdr, *rp_wd;
  const int* bcnt;
};

__global__ __launch_bounds__(256) void place_kernel(CSRB q) {
  __shared__ int cnt[256], off[256], sm[256];
  int g = blockIdx.x;
  const unsigned* st; unsigned short* csr; int* rp; int relFirst, relLast, n, cap, Etot;
  if (g < NBK_W)            { st = q.st_ww;  csr = q.c_ww;  rp = q.rp_ww;  relFirst = 0;         relLast = NBK_W - 1;     n = N_WORD; cap = CAP_WW;  Etot = E_WW; }
  else if (g < 2 * NBK_W)   { st = q.st_wwr; csr = q.c_wwr; rp = q.rp_wwr; relFirst = NBK_W;     relLast = 2 * NBK_W - 1; n = N_WORD; cap = CAP_WW;  Etot = E_WW; }
  else if (g < 3 * NBK_W)   { st = q.st_wdr; csr = q.c_wdr; rp = q.rp_wdr; relFirst = 2 * NBK_W; relLast = 3 * NBK_W - 1; n = N_WORD; cap = CAP_WDR; Etot = E_WD; }
  else                      { st = q.st_wd;  csr = q.c_wd;  rp = q.rp_wd;  relFirst = 3 * NBK_W; relLast = BKT - 1;       n = N_DOC;  cap = CAP_WD;  Etot = E_WD; }
  int cb = g - relFirst;
  int tid = threadIdx.x;
  int v = (tid < cb) ? q.bcnt[relFirst + tid] : 0;
  sm[tid] = v;
  __syncthreads();
  for (int o = 128; o > 0; o >>= 1) {
    if (tid < o) sm[tid] += sm[tid + o];
    __syncthreads();
  }
  int bstart = sm[0];
  if (g == relLast && tid == 0) rp[n] = Etot;   // tail sentinel
  __syncthreads();
  int node_base = cb << 8;
  int node_cnt = n - node_base; if (node_cnt > NPB) node_cnt = NPB;
  int ecnt = q.bcnt[g];
  const unsigned* w = st + (size_t)cb * cap;
  cnt[tid] = 0;
  __syncthreads();
  for (int j = tid; j < ecnt; j += 256) atomicAdd(&cnt[w[j] >> 16], 1);
  __syncthreads();
  int c = cnt[tid];
  sm[tid] = c;
  __syncthreads();
  for (int o = 1; o < 256; o <<= 1) {
    int add = (tid >= o) ? sm[tid - o] : 0;
    __syncthreads();
    sm[tid] += add;
    __syncthreads();
  }
  int ex = sm[tid] - c;
  off[tid] = ex;
  if (tid < node_cnt) rp[node_base + tid] = bstart + ex;
  __syncthreads();
  for (int j = tid; j < ecnt; j += 256) {
    unsigned e = w[j];
    int p = atomicAdd(&off[e >> 16], 1);
    csr[bstart + p] = (unsigned short)(e & 0xFFFFu);
  }
}

// ---------------- gathers ----------------------------------------------------
// Full-row (256 B) accumulate: 16-lane groups, 16-edge batches, degree-
// adaptive trip count (cnt is wave-uniform -> uniform branch, s_cbranch).
__device__ inline void accum_rel4(const uint4* __restrict__ Y,
                                  const unsigned short* __restrict__ csr,
                                  int beg, int end, int lane, int r, int g,
                                  int zrow, f32x2* __restrict__ f) {
  int deg = end - beg;
  if (deg <= 0) return;
  f32x2 a0 = {0.f, 0.f}, a1 = a0, a2 = a0, a3 = a0;
  for (int base = beg; base < end; base += 64) {
    int cnt = end - base; if (cnt > 64) cnt = 64;
    int ld = base + lane;
    int idx = (ld < end) ? (int)csr[ld] : zrow;   // OOR lanes -> zero row
    for (int j = 0; j < cnt; j += 16) {
      int nt = (cnt - j + 3) >> 2; if (nt > 4) nt = 4;   // wave-uniform
      uint4 u[4];
#pragma unroll
      for (int t = 0; t < 4; ++t) {
        if (t < nt) {
          int sv = __shfl(idx, j + (t << 2) + g, 64);  // group's edge src
          u[t] = Y[(unsigned)((sv << 4) + r)];
        }
      }
#pragma unroll
      for (int t = 0; t < 4; ++t) {
        if (t < nt) {
          a0 += (f32x2){bflo(u[t].x), bfhi(u[t].x)};
          a1 += (f32x2){bflo(u[t].y), bfhi(u[t].y)};
          a2 += (f32x2){bflo(u[t].z), bfhi(u[t].z)};
          a3 += (f32x2){bflo(u[t].w), bfhi(u[t].w)};
        }
      }
    }
  }
  float inv = 1.0f / (float)deg;
  f[0] += a0 * inv; f[1] += a1 * inv; f[2] += a2 * inv; f[3] += a3 * inv;
}

// Half-row (128 B) accumulate: 8-lane groups, 32-edge batches. Round-9 PMC:
// fixed 4-deep t-loop wasted half the loads on sentinel rows at deg~16
// (VALUBusy 80%, dur 112us). Degree-adaptive nt restores per-edge parity.
__device__ inline void accum_rel4h(const uint4* __restrict__ Y,
                                   const unsigned short* __restrict__ csr,
                                   int beg, int end, int lane, int r2, int g2,
                                   int zrow, f32x2* __restrict__ f) {
  int deg = end - beg;
  if (deg <= 0) return;
  f32x2 a0 = {0.f, 0.f}, a1 = a0, a2 = a0, a3 = a0;
  for (int base = beg; base < end; base += 64) {
    int cnt = end - base; if (cnt > 64) cnt = 64;
    int ld = base + lane;
    int idx = (ld < end) ? (int)csr[ld] : zrow;
    for (int j = 0; j < cnt; j += 32) {
      int nt = (cnt - j + 7) >> 3; if (nt > 4) nt = 4;   // wave-uniform
      uint4 u[4];
#pragma unroll
      for (int t = 0; t < 4; ++t) {
        if (t < nt) {
          int sv = __shfl(idx, j + (t << 3) + g2, 64);
          u[t] = Y[(unsigned)((sv << 3) + r2)];
        }
      }
#pragma unroll
      for (int t = 0; t < 4; ++t) {
        if (t < nt) {
          a0 += (f32x2){bflo(u[t].x), bfhi(u[t].x)};
          a1 += (f32x2){bflo(u[t].y), bfhi(u[t].y)};
          a2 += (f32x2){bflo(u[t].z), bfhi(u[t].z)};
          a3 += (f32x2){bflo(u[t].w), bfhi(u[t].w)};
        }
      }
    }
  }
  float inv = 1.0f / (float)deg;
  f[0] += a0 * inv; f[1] += a1 * inv; f[2] += a2 * inv; f[3] += a3 * inv;
}

__device__ inline void mean_write_h(int node, int r2, int g2,
                                    f32x2* __restrict__ A, unsigned* __restrict__ mT) {
#pragma unroll
  for (int i = 0; i < 4; ++i) {
    A[i].x += __shfl_xor(A[i].x, 8, 64);  A[i].y += __shfl_xor(A[i].y, 8, 64);
    A[i].x += __shfl_xor(A[i].x, 16, 64); A[i].y += __shfl_xor(A[i].y, 16, 64);
    A[i].x += __shfl_xor(A[i].x, 32, 64); A[i].y += __shfl_xor(A[i].y, 32, 64);
  }
  if (g2 == 0) {
    uint4 pk;
    pk.x = (unsigned)f2bf(A[0].x) | ((unsigned)f2bf(A[0].y) << 16);
    pk.y = (unsigned)f2bf(A[1].x) | ((unsigned)f2bf(A[1].y) << 16);
    pk.z = (unsigned)f2bf(A[2].x) | ((unsigned)f2bf(A[2].y) << 16);
    pk.w = (unsigned)f2bf(A[3].x) | ((unsigned)f2bf(A[3].y) << 16);
    ((uint4*)mT)[(unsigned)((node << 3) + r2)] = pk;
  }
}

// D4: layer-1 gather over TRANSFORMED full tables; fused self+bias+relu;
// writes FEATURE-SPLIT bf16 activations (Lo = dims 0-63, Hi = 64-127).
__global__ __launch_bounds__(256) void gather_all(
    const unsigned* __restrict__ y_ww, const unsigned* __restrict__ y_wwr,
    const unsigned* __restrict__ y_wdr, const unsigned* __restrict__ y_wd,
    const unsigned short* __restrict__ c_ww, const unsigned short* __restrict__ c_wwr,
    const unsigned short* __restrict__ c_wdr, const unsigned short* __restrict__ c_wd,
    const int* __restrict__ r_ww, const int* __restrict__ r_wwr,
    const int* __restrict__ r_wdr, const int* __restrict__ r_wd,
    const unsigned* __restrict__ tW, const unsigned* __restrict__ tD,
    const float* __restrict__ bW, const float* __restrict__ bD,
    unsigned* __restrict__ oWLo, unsigned* __restrict__ oWHi,
    unsigned* __restrict__ oDLo, unsigned* __restrict__ oDHi) {
  int gn = (blockIdx.x << 2) + (threadIdx.x >> 6);
  if (gn >= N_WORD + N_DOC) return;
  int lane = threadIdx.x & 63;
  int r = lane & 15, g = lane >> 4;
  f32x2 f[4];
#pragma unroll
  for (int i = 0; i < 4; ++i) f[i] = (f32x2){0.f, 0.f};
  bool isw = (gn < N_WORD);
  int node = isw ? gn : gn - N_WORD;
  if (isw) {
    accum_rel4((const uint4*)y_ww, c_ww, r_ww[node], r_ww[node + 1], lane, r, g, N_WORD, f);
    accum_rel4((const uint4*)y_wwr, c_wwr, r_wwr[node], r_wwr[node + 1], lane, r, g, N_WORD, f);
    accum_rel4((const uint4*)y_wdr, c_wdr, r_wdr[node], r_wdr[node + 1], lane, r, g, N_DOC, f);
  } else {
    accum_rel4((const uint4*)y_wd, c_wd, r_wd[node], r_wd[node + 1], lane, r, g, N_WORD, f);
  }
#pragma unroll
  for (int i = 0; i < 4; ++i) {
    f[i].x += __shfl_xor(f[i].x, 16, 64);
    f[i].y += __shfl_xor(f[i].y, 16, 64);
    f[i].x += __shfl_xor(f[i].x, 32, 64);
    f[i].y += __shfl_xor(f[i].y, 32, 64);
  }
  const unsigned* tS = isw ? tW : tD;
  uint4 tu = ((const uint4*)tS)[(unsigned)((node << 4) + r)];
  const float* bs = isw ? bW : bD;
  float4 bv0 = ((const float4*)bs)[2 * r];
  float4 bv1 = ((const float4*)bs)[2 * r + 1];
  f[0].x = fmaxf(f[0].x + bflo(tu.x) + bv0.x, 0.f);
  f[0].y = fmaxf(f[0].y + bfhi(tu.x) + bv0.y, 0.f);
  f[1].x = fmaxf(f[1].x + bflo(tu.y) + bv0.z, 0.f);
  f[1].y = fmaxf(f[1].y + bfhi(tu.y) + bv0.w, 0.f);
  f[2].x = fmaxf(f[2].x + bflo(tu.z) + bv1.x, 0.f);
  f[2].y = fmaxf(f[2].y + bfhi(tu.z) + bv1.y, 0.f);
  f[3].x = fmaxf(f[3].x + bflo(tu.w) + bv1.z, 0.f);
  f[3].y = fmaxf(f[3].y + bfhi(tu.w) + bv1.w, 0.f);
  if (g == 0) {                       // groups identical post-reduce
    uint4 pk;
    pk.x = (unsigned)f2bf(f[0].x) | ((unsigned)f2bf(f[0].y) << 16);
    pk.y = (unsigned)f2bf(f[1].x) | ((unsigned)f2bf(f[1].y) << 16);
    pk.z = (unsigned)f2bf(f[2].x) | ((unsigned)f2bf(f[2].y) << 16);
    pk.w = (unsigned)f2bf(f[3].x) | ((unsigned)f2bf(f[3].y) << 16);
    unsigned* o;
    if (isw) o = (r < 8) ? oWLo : oWHi;
    else     o = (r < 8) ? oDLo : oDHi;
    ((uint4*)o)[(unsigned)((node << 3) + (r & 7))] = pk;
  }
}

// D5: layer-2 RAW gather, FEATURE-SPLIT 2-pass. Per pass the active random
// footprint is one 6.4MB word half + 1.28MB doc half -> FETCH 171MB
// (measured r9, vs 219MB unsplit). With adaptive nt the VALU cost matches
// the unsplit version.
struct MT { const unsigned *yW, *yD; unsigned *mWW, *mWWR, *mWDR, *mWD; };

__global__ __launch_bounds__(256) void gather_mean(
    MT lo, MT hi,
    const unsigned short* __restrict__ c_ww, const unsigned short* __restrict__ c_wwr,
    const unsigned short* __restrict__ c_wdr, const unsigned short* __restrict__ c_wd,
    const int* __restrict__ r_ww, const int* __restrict__ r_wwr,
    const int* __restrict__ r_wdr, const int* __restrict__ r_wd) {
  int b = blockIdx.x;
  bool isLo = (b < GMB);
  const MT& m = isLo ? lo : hi;
  int gn = ((isLo ? b : b - GMB) << 2) + (threadIdx.x >> 6);
  if (gn >= N_WORD + N_DOC) return;
  int lane = threadIdx.x & 63;
  int r2 = lane & 7, g2 = lane >> 3;
  bool isw = (gn < N_WORD);
  int node = isw ? gn : gn - N_WORD;
  f32x2 A[4];
  if (isw) {
#pragma unroll
    for (int i = 0; i < 4; ++i) A[i] = (f32x2){0.f, 0.f};
    accum_rel4h((const uint4*)m.yW, c_ww, r_ww[node], r_ww[node + 1], lane, r2, g2, N_WORD, A);
    mean_write_h(node, r2, g2, A, m.mWW);
#pragma unroll
    for (int i = 0; i < 4; ++i) A[i] = (f32x2){0.f, 0.f};
    accum_rel4h((const uint4*)m.yW, c_wwr, r_wwr[node], r_wwr[node + 1], lane, r2, g2, N_WORD, A);
    mean_write_h(node, r2, g2, A, m.mWWR);
#pragma unroll
    for (int i = 0; i < 4; ++i) A[i] = (f32x2){0.f, 0.f};
    accum_rel4h((const uint4*)m.yD, c_wdr, r_wdr[node], r_wdr[node + 1], lane, r2, g2, N_DOC, A);
    mean_write_h(node, r2, g2, A, m.mWDR);
  } else {
#pragma unroll
    for (int i = 0; i < 4; ++i) A[i] = (f32x2){0.f, 0.f};
    accum_rel4h((const uint4*)m.yW, c_wd, r_wd[node], r_wd[node + 1], lane, r2, g2, N_WORD, A);
    mean_write_h(node, r2, g2, A, m.mWD);
  }
}

// ---------------------------------------------------------------------------
extern "C" void kernel_launch(void* const* d_in, const int* in_sizes, int n_in,
                              void* d_out, int out_size, void* d_ws, size_t ws_size,
                              hipStream_t stream) {
  const float* xw      = (const float*)d_in[0];
  const float* xd      = (const float*)d_in[1];
  const int*   ww_src  = (const int*)d_in[2];
  const int*   ww_dst  = (const int*)d_in[3];
  const int*   wwr_src = (const int*)d_in[4];
  const int*   wwr_dst = (const int*)d_in[5];
  const int*   wd_src  = (const int*)d_in[6];
  const int*   wd_dst  = (const int*)d_in[7];
  const int*   wdr_src = (const int*)d_in[8];
  const int*   wdr_dst = (const int*)d_in[9];
  const float* Ws1     = (const float*)d_in[10];
  const float* Wn1     = (const float*)d_in[11];
  const float* b1      = (const float*)d_in[12];
  const float* Ws2     = (const float*)d_in[13];
  const float* Wn2     = (const float*)d_in[14];
  const float* b2      = (const float*)d_in[15];
  const float* lin_w   = (const float*)d_in[16];
  const float* lin_b   = (const float*)d_in[17];
  float* out = (float*)d_out;

  // ---- workspace carve ----
  char* p = (char*)d_ws;
  auto alloc = [&](size_t nbytes) {
    char* r = p;
    p += (nbytes + 255) & ~(size_t)255;
    return r;
  };
  unsigned* twA  = (unsigned*)alloc((size_t)N_WORD * D_H * 2);  // bf16 self acc
  unsigned* tdA  = (unsigned*)alloc((size_t)N_DOC * D_H * 2);
  unsigned* xw1B = (unsigned*)alloc((size_t)N_WORD * D_H * 2 + 256);  // +zero row
  unsigned* yB2  = (unsigned*)alloc((size_t)N_WORD * D_H * 2 + 256); // +zero row
  unsigned* yBX  = (unsigned*)alloc((size_t)N_WORD * D_H * 2 + 256); // +zero row
  unsigned* ydB  = (unsigned*)alloc((size_t)N_DOC * D_H * 2 + 256);  // +zero row
  // feature-split x1 activations (+half-row sentinels)
  unsigned* yB0L  = (unsigned*)alloc((size_t)N_WORD * 64 * 2 + 128);
  unsigned* yB0H  = (unsigned*)alloc((size_t)N_WORD * 64 * 2 + 128);
  unsigned* xd1BL = (unsigned*)alloc((size_t)N_DOC * 64 * 2 + 128);
  unsigned* xd1BH = (unsigned*)alloc((size_t)N_DOC * 64 * 2 + 128);
  // staging-only buffer (st_wdr + st_wd)
  unsigned* yB1 = (unsigned*)alloc(((size_t)NBK_W * CAP_WDR + (size_t)NBK_D * CAP_WD) * 4);
  unsigned short* csr_ww  = (unsigned short*)alloc((size_t)E_WW * 2);
  unsigned short* csr_wwr = (unsigned short*)alloc((size_t)E_WW * 2);
  unsigned short* csr_wdr = (unsigned short*)alloc((size_t)E_WD * 2);
  unsigned short* csr_wd  = (unsigned short*)alloc((size_t)E_WD * 2);
  int* rp_ww  = (int*)alloc((size_t)(N_WORD + 1) * 4);
  int* rp_wwr = (int*)alloc((size_t)(N_WORD + 1) * 4);
  int* rp_wdr = (int*)alloc((size_t)(N_WORD + 1) * 4);
  int* rp_wd  = (int*)alloc((size_t)(N_DOC + 1) * 4);
  short* Bp1 = (short*)alloc((size_t)6 * 256 * 128 * 2);
  short* Bp2 = (short*)alloc((size_t)6 * 128 * 128 * 2);
  int* bcnt  = (int*)alloc((size_t)BKT * 4);
  float* bs1 = (float*)alloc(D_H * 4);
  float* bs2 = (float*)alloc(D_H * 4);
  // staging aliases (read by place; dead before gather_all writes x1 splits)
  unsigned* st_ww  = yB0L;
  unsigned* st_wwr = yB0H;
  unsigned* st_wdr = yB1;
  unsigned* st_wd  = st_wdr + (size_t)NBK_W * CAP_WDR;
  // mean-table aliases (transformed tables dead after D4)
  unsigned* mWWL  = yB2;  unsigned* mWWH  = yB2 + (size_t)N_WORD * 32;
  unsigned* mWWRL = xw1B; unsigned* mWWRH = xw1B + (size_t)N_WORD * 32;
  unsigned* mWDRL = yBX;  unsigned* mWDRH = yBX + (size_t)N_WORD * 32;
  unsigned* mWDL  = ydB;  unsigned* mWDH  = ydB + (size_t)N_DOC * 32;

  const int W1 = 256 * 128;

  // ---- D1: prep (pack + bias + bcnt zero + sentinels) ----
  prep_kernel<<<PACK_BLKS + 1, 256, 0, stream>>>(
      Ws1, Wn1, Ws2, Wn2, Bp1, Bp2, b1, b2, bs1, bs2, bcnt,
      yB2, xw1B, yBX, ydB, yB0L, yB0H, xd1BL, xd1BH);

  // ---- D2: LDS-sorted bin || layer-1 GEMM (overlapping pipes) ----
  G6 g1;
  g1.B[0] = Bp1 + 0 * W1; g1.C[0] = (unsigned short*)twA;   // word self
  g1.B[1] = Bp1 + 1 * W1; g1.C[1] = (unsigned short*)yB2;   // ww neigh
  g1.B[2] = Bp1 + 2 * W1; g1.C[2] = (unsigned short*)xw1B;  // wwr neigh
  g1.B[3] = Bp1 + 3 * W1; g1.C[3] = (unsigned short*)yBX;   // wd neigh
  g1.B[4] = Bp1 + 5 * W1; g1.C[4] = (unsigned short*)tdA;   // doc self
  g1.B[5] = Bp1 + 4 * W1; g1.C[5] = (unsigned short*)ydB;   // wdr neigh
  bin_gemm1<<<NBLK_TOT + NSTRIP, 256, 0, stream>>>(
      ww_src, ww_dst, wwr_src, wwr_dst, wdr_src, wdr_dst, wd_src, wd_dst,
      bcnt, st_ww, st_wwr, st_wdr, st_wd, xw, xd, g1);

  // ---- D3: place (CSR finalize) ----
  CSRB q;
  q.st_ww = st_ww; q.st_wwr = st_wwr; q.st_wdr = st_wdr; q.st_wd = st_wd;
  q.c_ww = csr_ww; q.c_wwr = csr_wwr; q.c_wdr = csr_wdr; q.c_wd = csr_wd;
  q.rp_ww = rp_ww; q.rp_wwr = rp_wwr; q.rp_wdr = rp_wdr; q.rp_wd = rp_wd;
  q.bcnt = bcnt;
  place_kernel<<<BKT, 256, 0, stream>>>(q);

  // ---- D4: layer-1 gather (full-row reads) -> SPLIT x1 (staging dead) ----
  gather_all<<<GMB, 256, 0, stream>>>(
      yB2, xw1B, ydB, yBX, csr_ww, csr_wwr, csr_wdr, csr_wd,
      rp_ww, rp_wwr, rp_wdr, rp_wd, twA, tdA, bs1, b1 + 256,
      yB0L, yB0H, xd1BL, xd1BH);

  // ---- D5: layer-2 SPLIT gather (2 passes, 7.7MB footprint each) ----
  MT lo, hi;
  lo.yW = yB0L; lo.yD = xd1BL;
  lo.mWW = mWWL; lo.mWWR = mWWRL; lo.mWDR = mWDRL; lo.mWD = mWDL;
  hi.yW = yB0H; hi.yD = xd1BH;
  hi.mWW = mWWH; hi.mWWR = mWWRH; hi.mWDR = mWDRH; hi.mWD = mWDH;
  gather_mean<<<2 * GMB, 256, 0, stream>>>(
      lo, hi, csr_ww, csr_wwr, csr_wdr, csr_wd,
      rp_ww, rp_wwr, rp_wdr, rp_wd);

  // ---- D6: fused layer-2 GEMM + readout (split A-operands) ----
  A2 aw, ad;
  aw.L[0] = yB0L;  aw.L[1] = mWWL;  aw.L[2] = mWWRL; aw.L[3] = mWDRL;
  aw.H[0] = yB0H;  aw.H[1] = mWWH;  aw.H[2] = mWWRH; aw.H[3] = mWDRH;
  ad.L[0] = xd1BL; ad.L[1] = mWDL;  ad.L[2] = nullptr; ad.L[3] = nullptr;
  ad.H[0] = xd1BH; ad.H[1] = mWDH;  ad.H[2] = nullptr; ad.H[3] = nullptr;
  gemm2f_kernel<<<NSTRIP, 256, 0, stream>>>(
      aw, ad, Bp2, bs2, b2 + 256, lin_w, lin_b, out);
}

// Round 11
// 358.525 us; speedup vs baseline: 1.1265x; 1.1265x over previous
//
#include <hip/hip_runtime.h>
#include <math.h>

#define N_WORD 50000
#define N_DOC  10000
#define E_WW   800000
#define E_WD   320000
#define D_IN   256
#define D_H    128

#define NPB    256            // nodes per bucket
#define NBK_W  196            // ceil(50000/256)
#define NBK_D  40             // ceil(10000/256)
#define BKT    (3 * NBK_W + NBK_D)   // 628 buckets total
#define EPB    8192           // edges per bin block (LDS-sorted)
#define NBLK_WW 98            // ceil(800000/8192)
#define NBLK_WD 40            // ceil(320000/8192)
#define NBLK_TOT (2 * NBLK_WW + 2 * NBLK_WD)   // 276
#define PACK_BLKS 145

// per-bucket staging caps (binomial mean + >10 sigma; graph fixed by seed)
#define CAP_WW  4736          // mean 4082, sigma ~64
#define CAP_WDR 2176          // mean 1633, sigma ~40
#define CAP_WD  8960          // mean 8000, sigma ~89

#define WSTRIP ((N_WORD + 63) / 64)  // 782
#define DSTRIP ((N_DOC + 63) / 64)   // 157
#define NSTRIP (WSTRIP + DSTRIP)     // 939

typedef __attribute__((ext_vector_type(8))) short short8;
typedef __attribute__((ext_vector_type(4))) float f32x4;
typedef __attribute__((ext_vector_type(2))) float f32x2;

__device__ inline unsigned short f2bf(float f) {  // fp32 -> bf16 bits, RNE
  unsigned u = __float_as_uint(f);
  u = (u + 0x7fffu + ((u >> 16) & 1u)) >> 16;
  return (unsigned short)u;
}

__device__ inline float bflo(unsigned u) { return __uint_as_float(u << 16); }
__device__ inline float bfhi(unsigned u) { return __uint_as_float(u & 0xffff0000u); }

// ---------------- GEMM body (layer 1): LDS-staged B shared across 4 waves ----
struct G6 { const short* B[6]; unsigned short* C[6]; };

#define BCH 16384   // shorts per staged chunk (32 KB)
#define W2SZ 16384  // shorts per layer-2 matrix (128x128)

template <int ABF, int K>
__device__ void gemm_body(const void* __restrict__ Aw, const void* __restrict__ Ad,
                          const G6& g, int blk, short* __restrict__ Bs) {
  constexpr int KT = K >> 5;          // 8 (K=256)
  constexpr int NCH = KT / 4;         // 32KB chunks per B matrix
  int tid = threadIdx.x;
  int wid = tid >> 6, lane = tid & 63;
  const void* A; int M, row0, h0, h1;
  if (blk < WSTRIP) { A = Aw; M = N_WORD; row0 = blk << 6; h0 = 0; h1 = 4; }
  else { A = Ad; M = N_DOC; row0 = (blk - WSTRIP) << 6; h0 = 4; h1 = 6; }
  int r = lane & 15, quad = lane >> 4;
  int m0 = row0 + wid * 16;
  int mA = m0 + r; if (mA >= M) mA = M - 1;   // clamp: garbage rows never stored
  short8 afr[KT];
  if (ABF) {
    const short* ap = (const short*)A + (size_t)mA * K + quad * 8;
#pragma unroll
    for (int kt = 0; kt < KT; ++kt) afr[kt] = *(const short8*)(ap + kt * 32);
  } else {
    const float* ap = (const float*)A + (size_t)mA * K + quad * 8;
#pragma unroll
    for (int kt = 0; kt < KT; ++kt) {
      float4 a0 = *(const float4*)(ap + kt * 32);
      float4 a1 = *(const float4*)(ap + kt * 32 + 4);
      short8 v;
      v[0] = (short)f2bf(a0.x); v[1] = (short)f2bf(a0.y);
      v[2] = (short)f2bf(a0.z); v[3] = (short)f2bf(a0.w);
      v[4] = (short)f2bf(a1.x); v[5] = (short)f2bf(a1.y);
      v[6] = (short)f2bf(a1.z); v[7] = (short)f2bf(a1.w);
      afr[kt] = v;
    }
  }
  for (int h = h0; h < h1; ++h) {
    const short* Bp = g.B[h];
    f32x4 acc[8];
#pragma unroll
    for (int nt = 0; nt < 8; ++nt) acc[nt] = (f32x4){0.f, 0.f, 0.f, 0.f};
    for (int c = 0; c < NCH; ++c) {
      const short* src = Bp + (size_t)c * BCH;
#pragma unroll
      for (int i = 0; i < 8; ++i) {
        int o = (i * 256 + tid) * 8;
        *(short8*)(Bs + o) = *(const short8*)(src + o);
      }
      __syncthreads();
#pragma unroll
      for (int ktl = 0; ktl < 4; ++ktl) {
        const short* bbase = Bs + ktl * 4096 + lane * 8;
#pragma unroll
        for (int nt = 0; nt < 8; ++nt) {
          short8 bf = *(const short8*)(bbase + nt * 512);
          acc[nt] = __builtin_amdgcn_mfma_f32_16x16x32_bf16(afr[c * 4 + ktl], bf, acc[nt], 0, 0, 0);
        }
      }
      __syncthreads();   // before next chunk/h overwrites Bs
    }
    // C/D: col = lane&15, row = quad*4 + rr  [m89-verified]
    unsigned short* C = g.C[h];
#pragma unroll
    for (int nt = 0; nt < 8; ++nt)
#pragma unroll
      for (int rr = 0; rr < 4; ++rr) {
        int row = m0 + quad * 4 + rr;
        if (row < M) C[(size_t)row * 128 + nt * 16 + r] = f2bf(acc[nt][rr]);
      }
  }
}

// ---------------- layer-2 fused GEMM: h2 = sum_s B_s * A_s; readout ----------
// Aggregate-first (mean commutes with W): A-sources are self + per-relation
// MEANS; all products accumulate into ONE acc; epilogue does bias+relu+
// linear+sigmoid -> writes the final scalar per node.
template <int NS>
__device__ void gemm2_fused(const unsigned* A0, const unsigned* A1,
                            const unsigned* A2, const unsigned* A3,
                            const short* B0, const short* B1,
                            const short* B2, const short* B3,
                            int M, int row0, const float* __restrict__ bias, int ob,
                            const float* __restrict__ lw, const float* __restrict__ lb,
                            float* __restrict__ out, short* __restrict__ Bs) {
  const unsigned* As[4] = {A0, A1, A2, A3};
  const short* Bm[4] = {B0, B1, B2, B3};
  int tid = threadIdx.x;
  int wid = tid >> 6, lane = tid & 63;
  int r = lane & 15, quad = lane >> 4;
  int m0 = row0 + wid * 16;
  int mA = m0 + r; if (mA >= M) mA = M - 1;
  short8 afr[NS][4];
#pragma unroll
  for (int s = 0; s < NS; ++s) {
    const short* ap = (const short*)As[s] + (size_t)mA * 128 + quad * 8;
#pragma unroll
    for (int kt = 0; kt < 4; ++kt) afr[s][kt] = *(const short8*)(ap + kt * 32);
  }
  f32x4 acc[8];
#pragma unroll
  for (int nt = 0; nt < 8; ++nt) acc[nt] = (f32x4){0.f, 0.f, 0.f, 0.f};
#pragma unroll
  for (int s = 0; s < NS; ++s) {
    const short* src = Bm[s];
#pragma unroll
    for (int i = 0; i < 8; ++i) {
      int o = (i * 256 + tid) * 8;
      *(short8*)(Bs + o) = *(const short8*)(src + o);
    }
    __syncthreads();
#pragma unroll
    for (int ktl = 0; ktl < 4; ++ktl) {
      const short* bbase = Bs + ktl * 4096 + lane * 8;
#pragma unroll
      for (int nt = 0; nt < 8; ++nt) {
        short8 bf = *(const short8*)(bbase + nt * 512);
        acc[nt] = __builtin_amdgcn_mfma_f32_16x16x32_bf16(afr[s][ktl], bf, acc[nt], 0, 0, 0);
      }
    }
    __syncthreads();
  }
  // epilogue: per row, p = sum_col relu(acc+bias)*lw; reduce over 16 col-lanes
  float bsv[8], lwv[8];
#pragma unroll
  for (int nt = 0; nt < 8; ++nt) { bsv[nt] = bias[nt * 16 + r]; lwv[nt] = lw[nt * 16 + r]; }
  float lbv = lb[0];
#pragma unroll
  for (int rr = 0; rr < 4; ++rr) {
    float p = 0.f;
#pragma unroll
    for (int nt = 0; nt < 8; ++nt) {
      float v = acc[nt][rr] + bsv[nt];
      v = fmaxf(v, 0.f);
      p += v * lwv[nt];
    }
    p += __shfl_xor(p, 1, 64);
    p += __shfl_xor(p, 2, 64);
    p += __shfl_xor(p, 4, 64);
    p += __shfl_xor(p, 8, 64);
    int row = m0 + quad * 4 + rr;
    if (r == 0 && row < M) out[ob + row] = 1.0f / (1.0f + expf(-(p + lbv)));
  }
}

__global__ __launch_bounds__(256, 2) void gemm2f_kernel(
    const unsigned* __restrict__ x1w, const unsigned* __restrict__ x1d,
    const unsigned* __restrict__ mww, const unsigned* __restrict__ mwwr,
    const unsigned* __restrict__ mwdr, const unsigned* __restrict__ mwd,
    const short* __restrict__ Bp2, const float* __restrict__ bsW,
    const float* __restrict__ bsD, const float* __restrict__ lw,
    const float* __restrict__ lb, float* __restrict__ out) {
  __shared__ short Bs[W2SZ];          // 32 KB
  int blk = blockIdx.x;
  if (blk < WSTRIP)
    gemm2_fused<4>(x1w, mww, mwwr, mwdr,
                   Bp2, Bp2 + W2SZ, Bp2 + 2 * W2SZ, Bp2 + 4 * W2SZ,
                   N_WORD, blk << 6, bsW, 0, lw, lb, out, Bs);
  else
    gemm2_fused<2>(x1d, mwd, nullptr, nullptr,
                   Bp2 + 5 * W2SZ, Bp2 + 3 * W2SZ, nullptr, nullptr,
                   N_DOC, (blk - WSTRIP) << 6, bsD, N_WORD, lw, lb, out, Bs);
}

// ---------------- prep: weight pack + bias combine + bcnt zero ---------------
// Zeroes sentinel rows (row N) of all tables the gathers read 4-rows-per-load.
__global__ __launch_bounds__(256) void prep_kernel(
    const float* __restrict__ Ws1, const float* __restrict__ Wn1,
    const float* __restrict__ Ws2, const float* __restrict__ Wn2,
    short* __restrict__ Bp1, short* __restrict__ Bp2,
    const float* __restrict__ b1, const float* __restrict__ b2,
    float* __restrict__ bs1, float* __restrict__ bs2, int* __restrict__ bcnt,
    unsigned* __restrict__ zA, unsigned* __restrict__ zB,
    unsigned* __restrict__ zC, unsigned* __restrict__ zD,
    unsigned* __restrict__ zE, unsigned* __restrict__ zF) {
  int b = blockIdx.x;
  if (b == PACK_BLKS) {               // zero block
    for (int i = threadIdx.x; i < BKT; i += 256) bcnt[i] = 0;
    if (threadIdx.x < 64) {           // sentinel rows for tail-free gathers
      zA[(size_t)N_WORD * 64 + threadIdx.x] = 0;
      zB[(size_t)N_WORD * 64 + threadIdx.x] = 0;
      zC[(size_t)N_WORD * 64 + threadIdx.x] = 0;
      zD[(size_t)N_DOC * 64 + threadIdx.x] = 0;
      zE[(size_t)N_WORD * 64 + threadIdx.x] = 0;   // yB0 (layer-2 raw gather)
      zF[(size_t)N_DOC * 64 + threadIdx.x] = 0;    // xd1B
    }
    return;
  }
  int tid = b * 256 + threadIdx.x;
  const int L1T = 6 * 4096;
  const int L2T = 6 * 2048;
  if (tid >= L1T + L2T) {             // bias combine tail
    int t = tid - (L1T + L2T);
    if (t < 128) bs1[t] = b1[t] + b1[128 + t] + b1[384 + t];
    else if (t < 256) { int u = t - 128; bs2[u] = b2[u] + b2[128 + u] + b2[384 + u]; }
    return;
  }
  const float *src0, *src1 = nullptr, *src2 = nullptr;
  short* dstp;
  int kt, nt, lane;
  if (tid < L1T) {
    int mat = tid / 4096, rem = tid % 4096;
    kt = rem / 512; nt = (rem / 64) % 8; lane = rem % 64;
    const int W1 = 256 * 128;
    if (mat == 0) { src0 = Ws1; src1 = Ws1 + W1; src2 = Ws1 + 3 * W1; }
    else if (mat <= 4) src0 = Wn1 + (size_t)(mat - 1) * W1;
    else src0 = Ws1 + 2 * W1;
    dstp = Bp1 + (size_t)mat * W1 + ((size_t)(kt * 8 + nt) * 64 + lane) * 8;
  } else {
    int t2 = tid - L1T;
    int mat = t2 / 2048, rem = t2 % 2048;
    kt = rem / 512; nt = (rem / 64) % 8; lane = rem % 64;
    if (mat == 0) { src0 = Ws2; src1 = Ws2 + W2SZ; src2 = Ws2 + 3 * W2SZ; }
    else if (mat <= 4) src0 = Wn2 + (size_t)(mat - 1) * W2SZ;
    else src0 = Ws2 + 2 * W2SZ;
    dstp = Bp2 + (size_t)mat * W2SZ + ((size_t)(kt * 8 + nt) * 64 + lane) * 8;
  }
  int n = nt * 16 + (lane & 15);
  int kb = kt * 32 + (lane >> 4) * 8;
  short8 v;
#pragma unroll
  for (int j = 0; j < 8; ++j) {
    float f = src0[(size_t)(kb + j) * 128 + n];
    if (src1) f += src1[(size_t)(kb + j) * 128 + n] + src2[(size_t)(kb + j) * 128 + n];
    v[j] = (short)f2bf(f);
  }
  *(short8*)dstp = v;
}

// ---------------- fused [LDS-sorted bin] || layer-1 GEMM ---------------------
__device__ inline void rel_map(int b, const int* wwd, const int* wwrd, const int* wdrd,
                               const int* wdd, const int*& dst, int& E, int& gbase, int& lb) {
  if (b < NBLK_WW) { dst = wwd; E = E_WW; gbase = 0; lb = b; }
  else if (b < 2 * NBLK_WW) { dst = wwrd; E = E_WW; gbase = NBK_W; lb = b - NBLK_WW; }
  else if (b < 2 * NBLK_WW + NBLK_WD) { dst = wdrd; E = E_WD; gbase = 2 * NBK_W; lb = b - 2 * NBLK_WW; }
  else { dst = wdd; E = E_WD; gbase = 3 * NBK_W; lb = b - 2 * NBLK_WW - NBLK_WD; }
}

struct BinLDS {
  unsigned buf[EPB];          // 32 KB sorted edge buffer
  int hist[NBK_W];
  int lofs[NBK_W];
  int gofs[NBK_W];            // global run base - local offset
  int lcur[NBK_W];
  int sm[256];
};

union FusedLDS {
  BinLDS bin;                 // ~36.8 KB (bin blocks)
  short bs[BCH];              // 32 KB B-stage (gemm blocks)
};

__global__ __launch_bounds__(256, 4) void bin_gemm1(
    const int* wws, const int* wwd, const int* wwrs, const int* wwrd,
    const int* wdrs, const int* wdrd, const int* wds, const int* wdd,
    int* bcnt, unsigned* st_ww, unsigned* st_wwr, unsigned* st_wdr, unsigned* st_wd,
    const float* __restrict__ Aw, const float* __restrict__ Ad, G6 g) {
  __shared__ FusedLDS U;
  int b = blockIdx.x;
  if (b >= NBLK_TOT) {
    gemm_body<0, 256>(Aw, Ad, g, b - NBLK_TOT, U.bs);
    return;
  }
  BinLDS& L = U.bin;
  const int* dst; int E, gbase, lb;
  rel_map(b, wwd, wwrd, wdrd, wdd, dst, E, gbase, lb);
  const int* src; unsigned* st; int cap;
  if (b < NBLK_WW) { src = wws; st = st_ww; cap = CAP_WW; }
  else if (b < 2 * NBLK_WW) { src = wwrs; st = st_wwr; cap = CAP_WW; }
  else if (b < 2 * NBLK_WW + NBLK_WD) { src = wdrs; st = st_wdr; cap = CAP_WDR; }
  else { src = wds; st = st_wd; cap = CAP_WD; }
  int tid = threadIdx.x;
  int e0 = lb * EPB;
  int ecnt = E - e0; if (ecnt > EPB) ecnt = EPB;
  if (tid < NBK_W) L.hist[tid] = 0;
  __syncthreads();
  // pass 1: histogram (dst cached in VGPRs for pass 2)
  int dcache[EPB / 256];
#pragma unroll
  for (int k = 0; k < EPB / 256; ++k) {
    int i = e0 + k * 256 + tid;
    int d = (i < E) ? dst[i] : -1;
    dcache[k] = d;
    if (d >= 0) atomicAdd(&L.hist[d >> 8], 1);
  }
  __syncthreads();
  // scan hist -> exclusive local offsets; reserve global runs
  {
    int v = (tid < NBK_W) ? L.hist[tid] : 0;
    L.sm[tid] = v;
    __syncthreads();
    for (int o = 1; o < 256; o <<= 1) {
      int add = (tid >= o) ? L.sm[tid - o] : 0;
      __syncthreads();
      L.sm[tid] += add;
      __syncthreads();
    }
    if (tid < NBK_W) {
      int ex = L.sm[tid] - v;
      L.lofs[tid] = ex;
      L.lcur[tid] = ex;
      int base = v ? atomicAdd(&bcnt[gbase + tid], v) : 0;
      L.gofs[tid] = (int)((size_t)tid * cap) + base - ex;
    }
  }
  __syncthreads();
  // pass 2: counting-sort scatter into LDS
#pragma unroll
  for (int k = 0; k < EPB / 256; ++k) {
    int d = dcache[k];
    if (d >= 0) {
      int i = e0 + k * 256 + tid;
      int bk = d >> 8;
      int p = atomicAdd(&L.lcur[bk], 1);
      L.buf[p] = ((unsigned)bk << 24) | ((unsigned)(d & 255) << 16) |
                 (unsigned)(src[i] & 0xFFFF);
    }
  }
  __syncthreads();
  // coalesced writeout: consecutive LDS entries -> consecutive staging addrs
#pragma unroll
  for (int k = 0; k < EPB / 256; ++k) {
    int p = k * 256 + tid;
    if (p < ecnt) {
      unsigned e = L.buf[p];
      st[L.gofs[e >> 24] + p] = e & 0x00FFFFFFu;
    }
  }
}

// ---------------- place: one block per 256-node bucket -----------------------
struct CSRB {
  const unsigned *st_ww, *st_wwr, *st_wdr, *st_wd;
  unsigned short *c_ww, *c_wwr, *c_wdr, *c_wd;
  int *rp_ww, *rp_wwr, *rp_wdr, *rp_wd;
  const int* bcnt;
};

__global__ __launch_bounds__(256) void place_kernel(CSRB q) {
  __shared__ int cnt[256], off[256], sm[256];
  int g = blockIdx.x;
  const unsigned* st; unsigned short* csr; int* rp; int relFirst, relLast, n, cap, Etot;
  if (g < NBK_W)            { st = q.st_ww;  csr = q.c_ww;  rp = q.rp_ww;  relFirst = 0;         relLast = NBK_W - 1;     n = N_WORD; cap = CAP_WW;  Etot = E_WW; }
  else if (g < 2 * NBK_W)   { st = q.st_wwr; csr = q.c_wwr; rp = q.rp_wwr; relFirst = NBK_W;     relLast = 2 * NBK_W - 1; n = N_WORD; cap = CAP_WW;  Etot = E_WW; }
  else if (g < 3 * NBK_W)   { st = q.st_wdr; csr = q.c_wdr; rp = q.rp_wdr; relFirst = 2 * NBK_W; relLast = 3 * NBK_W - 1; n = N_WORD; cap = CAP_WDR; Etot = E_WD; }
  else                      { st = q.st_wd;  csr = q.c_wd;  rp = q.rp_wd;  relFirst = 3 * NBK_W; relLast = BKT - 1;       n = N_DOC;  cap = CAP_WD;  Etot = E_WD; }
  int cb = g - relFirst;
  int tid = threadIdx.x;
  int v = (tid < cb) ? q.bcnt[relFirst + tid] : 0;
  sm[tid] = v;
  __syncthreads();
  for (int o = 128; o > 0; o >>= 1) {
    if (tid < o) sm[tid] += sm[tid + o];
    __syncthreads();
  }
  int bstart = sm[0];
  if (g == relLast && tid == 0) rp[n] = Etot;   // tail sentinel
  __syncthreads();
  int node_base = cb << 8;
  int node_cnt = n - node_base; if (node_cnt > NPB) node_cnt = NPB;
  int ecnt = q.bcnt[g];
  const unsigned* w = st + (size_t)cb * cap;
  cnt[tid] = 0;
  __syncthreads();
  for (int j = tid; j < ecnt; j += 256) atomicAdd(&cnt[w[j] >> 16], 1);
  __syncthreads();
  int c = cnt[tid];
  sm[tid] = c;
  __syncthreads();
  for (int o = 1; o < 256; o <<= 1) {
    int add = (tid >= o) ? sm[tid - o] : 0;
    __syncthreads();
    sm[tid] += add;
    __syncthreads();
  }
  int ex = sm[tid] - c;
  off[tid] = ex;
  if (tid < node_cnt) rp[node_base + tid] = bstart + ex;
  __syncthreads();
  for (int j = tid; j < ecnt; j += 256) {
    unsigned e = w[j];
    int p = atomicAdd(&off[e >> 16], 1);
    csr[bstart + p] = (unsigned short)(e & 0xFFFFu);
  }
}

// ---------------- gathers: 4 rows per dwordx4, group-parallel ----------------
// Proven round-5 structure (28 VGPR, 75% occ): fixed 4-deep batches. The
// r9/r10 split/adaptive variants all regressed (latency-bound; fewer bytes
// in flight per wave costs more than the FETCH savings).
__device__ inline void accum_rel4(const uint4* __restrict__ Y,
                                  const unsigned short* __restrict__ csr,
                                  int beg, int end, int lane, int r, int g,
                                  int zrow, f32x2* __restrict__ f) {
  int deg = end - beg;
  if (deg <= 0) return;
  f32x2 a0 = {0.f, 0.f}, a1 = a0, a2 = a0, a3 = a0;
  for (int base = beg; base < end; base += 64) {
    int cnt = end - base; if (cnt > 64) cnt = 64;
    int ld = base + lane;
    int idx = (ld < end) ? (int)csr[ld] : zrow;   // OOR lanes -> zero row
    for (int j = 0; j < cnt; j += 16) {
      uint4 u[4];
#pragma unroll
      for (int t = 0; t < 4; ++t) {
        int sv = __shfl(idx, j + (t << 2) + g, 64);  // group's edge src
        u[t] = Y[(unsigned)((sv << 4) + r)];
      }
#pragma unroll
      for (int t = 0; t < 4; ++t) {
        a0 += (f32x2){bflo(u[t].x), bfhi(u[t].x)};
        a1 += (f32x2){bflo(u[t].y), bfhi(u[t].y)};
        a2 += (f32x2){bflo(u[t].z), bfhi(u[t].z)};
        a3 += (f32x2){bflo(u[t].w), bfhi(u[t].w)};
      }
    }
  }
  float inv = 1.0f / (float)deg;
  f[0] += a0 * inv; f[1] += a1 * inv; f[2] += a2 * inv; f[3] += a3 * inv;
}

// D4: layer-1 gather over TRANSFORMED tables; fused self+bias+relu; writes
// bf16 activations (word -> oW16, doc -> oD16).
__global__ __launch_bounds__(256) void gather_all(
    const unsigned* __restrict__ y_ww, const unsigned* __restrict__ y_wwr,
    const unsigned* __restrict__ y_wdr, const unsigned* __restrict__ y_wd,
    const unsigned short* __restrict__ c_ww, const unsigned short* __restrict__ c_wwr,
    const unsigned short* __restrict__ c_wdr, const unsigned short* __restrict__ c_wd,
    const int* __restrict__ r_ww, const int* __restrict__ r_wwr,
    const int* __restrict__ r_wdr, const int* __restrict__ r_wd,
    const unsigned* __restrict__ tW, const unsigned* __restrict__ tD,
    const float* __restrict__ bW, const float* __restrict__ bD,
    unsigned* __restrict__ oW16, unsigned* __restrict__ oD16) {
  int gn = (blockIdx.x << 2) + (threadIdx.x >> 6);
  if (gn >= N_WORD + N_DOC) return;
  int lane = threadIdx.x & 63;
  int r = lane & 15, g = lane >> 4;
  f32x2 f[4];
#pragma unroll
  for (int i = 0; i < 4; ++i) f[i] = (f32x2){0.f, 0.f};
  bool isw = (gn < N_WORD);
  int node = isw ? gn : gn - N_WORD;
  if (isw) {
    accum_rel4((const uint4*)y_ww, c_ww, r_ww[node], r_ww[node + 1], lane, r, g, N_WORD, f);
    accum_rel4((const uint4*)y_wwr, c_wwr, r_wwr[node], r_wwr[node + 1], lane, r, g, N_WORD, f);
    accum_rel4((const uint4*)y_wdr, c_wdr, r_wdr[node], r_wdr[node + 1], lane, r, g, N_DOC, f);
  } else {
    accum_rel4((const uint4*)y_wd, c_wd, r_wd[node], r_wd[node + 1], lane, r, g, N_WORD, f);
  }
#pragma unroll
  for (int i = 0; i < 4; ++i) {
    f[i].x += __shfl_xor(f[i].x, 16, 64);
    f[i].y += __shfl_xor(f[i].y, 16, 64);
    f[i].x += __shfl_xor(f[i].x, 32, 64);
    f[i].y += __shfl_xor(f[i].y, 32, 64);
  }
  const unsigned* tS = isw ? tW : tD;
  uint4 tu = ((const uint4*)tS)[(unsigned)((node << 4) + r)];
  const float* bs = isw ? bW : bD;
  float4 bv0 = ((const float4*)bs)[2 * r];
  float4 bv1 = ((const float4*)bs)[2 * r + 1];
  f[0].x = fmaxf(f[0].x + bflo(tu.x) + bv0.x, 0.f);
  f[0].y = fmaxf(f[0].y + bfhi(tu.x) + bv0.y, 0.f);
  f[1].x = fmaxf(f[1].x + bflo(tu.y) + bv0.z, 0.f);
  f[1].y = fmaxf(f[1].y + bfhi(tu.y) + bv0.w, 0.f);
  f[2].x = fmaxf(f[2].x + bflo(tu.z) + bv1.x, 0.f);
  f[2].y = fmaxf(f[2].y + bfhi(tu.z) + bv1.y, 0.f);
  f[3].x = fmaxf(f[3].x + bflo(tu.w) + bv1.z, 0.f);
  f[3].y = fmaxf(f[3].y + bfhi(tu.w) + bv1.w, 0.f);
  if (g == 0) {                       // groups identical post-reduce
    uint4 pk;
    pk.x = (unsigned)f2bf(f[0].x) | ((unsigned)f2bf(f[0].y) << 16);
    pk.y = (unsigned)f2bf(f[1].x) | ((unsigned)f2bf(f[1].y) << 16);
    pk.z = (unsigned)f2bf(f[2].x) | ((unsigned)f2bf(f[2].y) << 16);
    pk.w = (unsigned)f2bf(f[3].x) | ((unsigned)f2bf(f[3].y) << 16);
    unsigned* o = isw ? oW16 : oD16;
    ((uint4*)o)[(unsigned)((node << 4) + r)] = pk;
  }
}

// D5: layer-2 RAW gather (aggregate-first). Reads yB0 (word acts, 12.8MB,
// shared by ww/wwr/wd) + xd1B (doc acts, 2.56MB, L2-resident) -- 15.4MB
// footprint. Writes per-relation bf16 mean tables.
__device__ inline void mean_write(int node, int lane, int r, int g,
                                  f32x2* __restrict__ A, unsigned* __restrict__ mT) {
#pragma unroll
  for (int i = 0; i < 4; ++i) {
    A[i].x += __shfl_xor(A[i].x, 16, 64);
    A[i].y += __shfl_xor(A[i].y, 16, 64);
    A[i].x += __shfl_xor(A[i].x, 32, 64);
    A[i].y += __shfl_xor(A[i].y, 32, 64);
  }
  if (g == 0) {
    uint4 pk;
    pk.x = (unsigned)f2bf(A[0].x) | ((unsigned)f2bf(A[0].y) << 16);
    pk.y = (unsigned)f2bf(A[1].x) | ((unsigned)f2bf(A[1].y) << 16);
    pk.z = (unsigned)f2bf(A[2].x) | ((unsigned)f2bf(A[2].y) << 16);
    pk.w = (unsigned)f2bf(A[3].x) | ((unsigned)f2bf(A[3].y) << 16);
    ((uint4*)mT)[(unsigned)((node << 4) + r)] = pk;
  }
}

__global__ __launch_bounds__(256) void gather_mean(
    const unsigned* __restrict__ yW, const unsigned* __restrict__ yD,
    const unsigned short* __restrict__ c_ww, const unsigned short* __restrict__ c_wwr,
    const unsigned short* __restrict__ c_wdr, const unsigned short* __restrict__ c_wd,
    const int* __restrict__ r_ww, const int* __restrict__ r_wwr,
    const int* __restrict__ r_wdr, const int* __restrict__ r_wd,
    unsigned* __restrict__ mWW, unsigned* __restrict__ mWWR,
    unsigned* __restrict__ mWDR, unsigned* __restrict__ mWD) {
  int gn = (blockIdx.x << 2) + (threadIdx.x >> 6);
  if (gn >= N_WORD + N_DOC) return;
  int lane = threadIdx.x & 63;
  int r = lane & 15, g = lane >> 4;
  bool isw = (gn < N_WORD);
  int node = isw ? gn : gn - N_WORD;
  f32x2 A[4];
  if (isw) {
#pragma unroll
    for (int i = 0; i < 4; ++i) A[i] = (f32x2){0.f, 0.f};
    accum_rel4((const uint4*)yW, c_ww, r_ww[node], r_ww[node + 1], lane, r, g, N_WORD, A);
    mean_write(node, lane, r, g, A, mWW);
#pragma unroll
    for (int i = 0; i < 4; ++i) A[i] = (f32x2){0.f, 0.f};
    accum_rel4((const uint4*)yW, c_wwr, r_wwr[node], r_wwr[node + 1], lane, r, g, N_WORD, A);
    mean_write(node, lane, r, g, A, mWWR);
#pragma unroll
    for (int i = 0; i < 4; ++i) A[i] = (f32x2){0.f, 0.f};
    accum_rel4((const uint4*)yD, c_wdr, r_wdr[node], r_wdr[node + 1], lane, r, g, N_DOC, A);
    mean_write(node, lane, r, g, A, mWDR);
  } else {
#pragma unroll
    for (int i = 0; i < 4; ++i) A[i] = (f32x2){0.f, 0.f};
    accum_rel4((const uint4*)yW, c_wd, r_wd[node], r_wd[node + 1], lane, r, g, N_WORD, A);
    mean_write(node, lane, r, g, A, mWD);
  }
}

// ---------------------------------------------------------------------------
extern "C" void kernel_launch(void* const* d_in, const int* in_sizes, int n_in,
                              void* d_out, int out_size, void* d_ws, size_t ws_size,
                              hipStream_t stream) {
  const float* xw      = (const float*)d_in[0];
  const float* xd      = (const float*)d_in[1];
  const int*   ww_src  = (const int*)d_in[2];
  const int*   ww_dst  = (const int*)d_in[3];
  const int*   wwr_src = (const int*)d_in[4];
  const int*   wwr_dst = (const int*)d_in[5];
  const int*   wd_src  = (const int*)d_in[6];
  const int*   wd_dst  = (const int*)d_in[7];
  const int*   wdr_src = (const int*)d_in[8];
  const int*   wdr_dst = (const int*)d_in[9];
  const float* Ws1     = (const float*)d_in[10];
  const float* Wn1     = (const float*)d_in[11];
  const float* b1      = (const float*)d_in[12];
  const float* Ws2     = (const float*)d_in[13];
  const float* Wn2     = (const float*)d_in[14];
  const float* b2      = (const float*)d_in[15];
  const float* lin_w   = (const float*)d_in[16];
  const float* lin_b   = (const float*)d_in[17];
  float* out = (float*)d_out;

  // ---- workspace carve (staging aliases yB0/yB1 pre-place) ----
  char* p = (char*)d_ws;
  auto alloc = [&](size_t nbytes) {
    char* r = p;
    p += (nbytes + 255) & ~(size_t)255;
    return r;
  };
  unsigned* twA  = (unsigned*)alloc((size_t)N_WORD * D_H * 2);  // bf16 self acc
  unsigned* tdA  = (unsigned*)alloc((size_t)N_DOC * D_H * 2);
  unsigned* xw1B = (unsigned*)alloc((size_t)N_WORD * D_H * 2 + 256);  // +zero row
  unsigned* xd1B = (unsigned*)alloc((size_t)N_DOC * D_H * 2 + 256);   // +zero row
  unsigned* yB0 = (unsigned*)alloc((size_t)N_WORD * D_H * 2 + 256);   // +zero row
  // yB1 is staging-only (st_wdr + st_wd): sized to actual need
  unsigned* yB1 = (unsigned*)alloc(((size_t)NBK_W * CAP_WDR + (size_t)NBK_D * CAP_WD) * 4);
  unsigned* yB2 = (unsigned*)alloc((size_t)N_WORD * D_H * 2 + 256);   // +zero row
  unsigned* ydB = (unsigned*)alloc((size_t)N_DOC * D_H * 2 + 256);    // +zero row
  unsigned short* csr_ww  = (unsigned short*)alloc((size_t)E_WW * 2);
  unsigned short* csr_wwr = (unsigned short*)alloc((size_t)E_WW * 2);
  unsigned short* csr_wdr = (unsigned short*)alloc((size_t)E_WD * 2);
  unsigned short* csr_wd  = (unsigned short*)alloc((size_t)E_WD * 2);
  int* rp_ww  = (int*)alloc((size_t)(N_WORD + 1) * 4);
  int* rp_wwr = (int*)alloc((size_t)(N_WORD + 1) * 4);
  int* rp_wdr = (int*)alloc((size_t)(N_WORD + 1) * 4);
  int* rp_wd  = (int*)alloc((size_t)(N_DOC + 1) * 4);
  short* Bp1 = (short*)alloc((size_t)6 * 256 * 128 * 2);
  short* Bp2 = (short*)alloc((size_t)6 * 128 * 128 * 2);
  int* bcnt  = (int*)alloc((size_t)BKT * 4);
  float* bs1 = (float*)alloc(D_H * 4);
  float* bs2 = (float*)alloc(D_H * 4);
  unsigned* yBX = (unsigned*)alloc((size_t)N_WORD * D_H * 2 + 256);   // +zero row
  // staging aliases (read by place; dead before gather1 writes yB0)
  unsigned* st_ww  = yB0;
  unsigned* st_wwr = st_ww + (size_t)NBK_W * CAP_WW;
  unsigned* st_wdr = yB1;
  unsigned* st_wd  = st_wdr + (size_t)NBK_W * CAP_WDR;

  const int W1 = 256 * 128;

  // ---- D1: prep (pack + bias + bcnt zero + sentinels incl. yB0/xd1B) ----
  prep_kernel<<<PACK_BLKS + 1, 256, 0, stream>>>(
      Ws1, Wn1, Ws2, Wn2, Bp1, Bp2, b1, b2, bs1, bs2, bcnt,
      yB2, xw1B, yBX, ydB, yB0, xd1B);

  // ---- D2: LDS-sorted bin || layer-1 GEMM (overlapping pipes) ----
  G6 g1;
  g1.B[0] = Bp1 + 0 * W1; g1.C[0] = (unsigned short*)twA;   // word self
  g1.B[1] = Bp1 + 1 * W1; g1.C[1] = (unsigned short*)yB2;   // ww neigh
  g1.B[2] = Bp1 + 2 * W1; g1.C[2] = (unsigned short*)xw1B;  // wwr neigh
  g1.B[3] = Bp1 + 3 * W1; g1.C[3] = (unsigned short*)yBX;   // wd neigh
  g1.B[4] = Bp1 + 5 * W1; g1.C[4] = (unsigned short*)tdA;   // doc self
  g1.B[5] = Bp1 + 4 * W1; g1.C[5] = (unsigned short*)ydB;   // wdr neigh
  bin_gemm1<<<NBLK_TOT + NSTRIP, 256, 0, stream>>>(
      ww_src, ww_dst, wwr_src, wwr_dst, wdr_src, wdr_dst, wd_src, wd_dst,
      bcnt, st_ww, st_wwr, st_wdr, st_wd, xw, xd, g1);

  // ---- D3: place (CSR finalize) ----
  CSRB q;
  q.st_ww = st_ww; q.st_wwr = st_wwr; q.st_wdr = st_wdr; q.st_wd = st_wd;
  q.c_ww = csr_ww; q.c_wwr = csr_wwr; q.c_wdr = csr_wdr; q.c_wd = csr_wd;
  q.rp_ww = rp_ww; q.rp_wwr = rp_wwr; q.rp_wdr = rp_wdr; q.rp_wd = rp_wd;
  q.bcnt = bcnt;
  place_kernel<<<BKT, 256, 0, stream>>>(q);

  // ---- D4: layer-1 gather (transformed tables -> yB0 word / xd1B doc) ----
  gather_all<<<(N_WORD + N_DOC + 3) / 4, 256, 0, stream>>>(
      yB2, xw1B, ydB, yBX, csr_ww, csr_wwr, csr_wdr, csr_wd,
      rp_ww, rp_wwr, rp_wdr, rp_wd, twA, tdA, bs1, b1 + 256,
      yB0, xd1B);

  // ---- D5: layer-2 RAW gather (15.4MB footprint) -> per-relation means ----
  // mean tables reuse the now-dead transformed-table buffers
  gather_mean<<<(N_WORD + N_DOC + 3) / 4, 256, 0, stream>>>(
      yB0, xd1B, csr_ww, csr_wwr, csr_wdr, csr_wd,
      rp_ww, rp_wwr, rp_wdr, rp_wd,
      yB2 /*mWW*/, xw1B /*mWWR*/, yBX /*mWDR*/, ydB /*mWD*/);

  // ---- D6: fused layer-2 GEMM + readout (mean commutes with W) ----
  gemm2f_kernel<<<NSTRIP, 256, 0, stream>>>(
      yB0, xd1B, yB2, xw1B, yBX, ydB, Bp2, bs2, b2 + 256,
      lin_w, lin_b, out);
}